// Round 7
// baseline (129.536 us; speedup 1.0000x reference)
//
#include <hip/hip_runtime.h>

#define NT1 512
#define NT2 256

struct WPtrs { const float* W[7]; const float* Bv[7]; };

// K2 state swizzle (unchanged from R4/R5)
__device__ __forceinline__ int scr(int ci) { return ci ^ ((ci >> 4) & 7); }

__device__ __forceinline__ float4 relu4(float4 a) {
  return make_float4(fmaxf(a.x,0.f), fmaxf(a.y,0.f), fmaxf(a.z,0.f), fmaxf(a.w,0.f));
}

__device__ __forceinline__ void fma4(float4& acc, float s, const float4& wv) {
  acc.x = fmaf(s, wv.x, acc.x); acc.y = fmaf(s, wv.y, acc.y);
  acc.z = fmaf(s, wv.z, acc.z); acc.w = fmaf(s, wv.w, acc.w);
}

// K1 level transform. State: plane h (channel half) at chunk h*1024 + row.
// Row r = t*K + k. Child (k,t) reads parents p0 = 2t*Kp + kp, p1 = p0 + Kp.
// th = tid&1 picks channel quad; g = tid>>1 -> (k, tIdx). All LDS addresses
// are one base + compile-time immediates (item stride = 256 chunks = 4096 B).
template<int LVL>
__device__ __forceinline__ void k1_level(const float4* __restrict__ src,
                                         float4* __restrict__ dst,
                                         const float* __restrict__ Wl,
                                         const float* __restrict__ Bl,
                                         int g, int th) {
  constexpr int K  = 1 << LVL;
  constexpr int Kp = K >> 1;
  const int k = g & (K - 1);
  const int tIdx = g >> LVL;
  const int kp = k >> 1;
  const float4* wp = (const float4*)(Wl + k * 128 + th * 4);
  float4 wa0 = wp[0],  wa1 = wp[2],  wa2 = wp[4],  wa3 = wp[6];
  float4 wa4 = wp[8],  wa5 = wp[10], wa6 = wp[12], wa7 = wp[14];
  float4 wb0 = wp[16], wb1 = wp[18], wb2 = wp[20], wb3 = wp[22];
  float4 wb4 = wp[24], wb5 = wp[26], wb6 = wp[28], wb7 = wp[30];
  const float4 bias = *(const float4*)(Bl + k * 8 + th * 4);
  const int rbase = 2 * tIdx * Kp + kp;          // parent row base (plane 0)
  const int wbase = th * 1024 + tIdx * K + k;    // child write base
#pragma unroll
  for (int i = 0; i < 4; ++i) {
    float4 A0 = src[rbase + 256*i];
    float4 A1 = src[rbase + 256*i + 1024];
    float4 C0 = src[rbase + 256*i + Kp];
    float4 C1 = src[rbase + 256*i + Kp + 1024];
    float4 a = bias;
    fma4(a, A0.x, wa0); fma4(a, A0.y, wa1); fma4(a, A0.z, wa2); fma4(a, A0.w, wa3);
    fma4(a, A1.x, wa4); fma4(a, A1.y, wa5); fma4(a, A1.z, wa6); fma4(a, A1.w, wa7);
    fma4(a, C0.x, wb0); fma4(a, C0.y, wb1); fma4(a, C0.z, wb2); fma4(a, C0.w, wb3);
    fma4(a, C1.x, wb4); fma4(a, C1.y, wb5); fma4(a, C1.z, wb6); fma4(a, C1.w, wb7);
    dst[wbase + 256*i] = relu4(a);
  }
}

__global__ __launch_bounds__(NT1, 2) void bfly_k1(
    const float* __restrict__ x, const float* __restrict__ F,
    const float* __restrict__ fbias, WPtrs P, float* __restrict__ ws)
{
  __shared__ float4 sA[2048];
  __shared__ float4 sB[2048];
  const int tid = threadIdx.x;
  const int b = blockIdx.x;
  const int th = tid & 1;
  const int g  = tid >> 1;

  // phase 1: input conv (kernel=16, stride=16); write plane-major
  {
    const float4* Fp = (const float4*)(F + th * 4);   // F[f*8 + th*4] -> idx f*2
    float4 f0 = Fp[0],  f1 = Fp[2],  f2 = Fp[4],  f3 = Fp[6];
    float4 f4 = Fp[8],  f5 = Fp[10], f6 = Fp[12], f7 = Fp[14];
    float4 f8 = Fp[16], f9 = Fp[18], f10 = Fp[20], f11 = Fp[22];
    float4 f12 = Fp[24], f13 = Fp[26], f14 = Fp[28], f15 = Fp[30];
    const float4 bias = *(const float4*)(fbias + th * 4);
    const float* xb = x + (size_t)b * 16384;
#pragma unroll
    for (int i = 0; i < 4; ++i) {
      int n = g + i * 256;
      const float4* xr = (const float4*)(xb + n * 16);
      float4 x0 = xr[0], x1 = xr[1], x2 = xr[2], x3 = xr[3];
      float4 a = bias;
      fma4(a, x0.x, f0);  fma4(a, x0.y, f1);  fma4(a, x0.z, f2);  fma4(a, x0.w, f3);
      fma4(a, x1.x, f4);  fma4(a, x1.y, f5);  fma4(a, x1.z, f6);  fma4(a, x1.w, f7);
      fma4(a, x2.x, f8);  fma4(a, x2.y, f9);  fma4(a, x2.z, f10); fma4(a, x2.w, f11);
      fma4(a, x3.x, f12); fma4(a, x3.y, f13); fma4(a, x3.z, f14); fma4(a, x3.w, f15);
      sA[th * 1024 + n] = relu4(a);
    }
  }
  __syncthreads();

  k1_level<1>(sA, sB, P.W[0], P.Bv[0], g, th); __syncthreads();
  k1_level<2>(sB, sA, P.W[1], P.Bv[1], g, th); __syncthreads();
  k1_level<3>(sA, sB, P.W[2], P.Bv[2], g, th); __syncthreads();
  k1_level<4>(sB, sA, P.W[3], P.Bv[3], g, th); __syncthreads();
  k1_level<5>(sA, sB, P.W[4], P.Bv[4], g, th); __syncthreads();
  k1_level<6>(sB, sA, P.W[5], P.Bv[5], g, th); __syncthreads();
  k1_level<7>(sA, sB, P.W[6], P.Bv[6], g, th); __syncthreads();

  // level-7 state in sB (plane-major). ws[j][b][t][c]: j = r&127, t = r>>7.
#pragma unroll
  for (int it = 0; it < 4; ++it) {
    int o = tid + it * 512;
    int r = o & 1023, h = o >> 10;
    float4 v = sB[o];
    int j = r & 127, t = r >> 7;
    *(float4*)(ws + (size_t)j * 65536 + b * 64 + t * 8 + h * 4) = v;
  }
}

// ---------------- K2: levels 8..10 + dense, weight-stationary (unchanged) ----------------
__global__ __launch_bounds__(NT2, 4) void bfly_k2(
    const float* __restrict__ ws,
    const float* __restrict__ W8, const float* __restrict__ B8,
    const float* __restrict__ W9, const float* __restrict__ B9,
    const float* __restrict__ W10, const float* __restrict__ B10,
    const float* __restrict__ fea, float* __restrict__ out)
{
  __shared__ float4 sA[512], sB[512];    // 32 batches x 16 chunks, ping-pong
  __shared__ float swt[2928];            // W8|W9|W10|B8|B9|B10|FEA
  const int tid = threadIdx.x;
  const int j = blockIdx.x, b0 = blockIdx.y * 32;
  const int th = tid & 1, g = tid >> 1;  // 128 groups

  {
    const float4* s4 = (const float4*)(ws + (size_t)j*65536 + (size_t)b0*64);
#pragma unroll
    for (int it = 0; it < 2; ++it) {
      int idx = tid + it*256;            // b_l*16 + chunk
      sA[scr(idx)] = s4[idx];
    }
  }
  {
    float4* d = (float4*)swt;
    for (int i = tid; i < 64;  i += NT2) d[i]       = ((const float4*)(W8  + j*256 ))[i];
    for (int i = tid; i < 128; i += NT2) d[64+i]    = ((const float4*)(W9  + j*512 ))[i];
    for (int i = tid; i < 256; i += NT2) d[192+i]   = ((const float4*)(W10 + j*1024))[i];
    if (tid < 4)  d[448+tid] = ((const float4*)(B8  + j*16))[tid];
    if (tid < 8)  d[452+tid] = ((const float4*)(B9  + j*32))[tid];
    if (tid < 16) d[460+tid] = ((const float4*)(B10 + j*64))[tid];
    for (int i = tid; i < 256; i += NT2) d[476+i]   = ((const float4*)(fea + j*1024))[i];
  }
  __syncthreads();

  auto loadW = [&](int woff, int boff, int k_l, float4* w4, float4& bias) {
#pragma unroll
    for (int s = 0; s < 2; ++s)
#pragma unroll
      for (int c = 0; c < 8; ++c)
        w4[s*8+c] = *(const float4*)(swt + woff + k_l*128 + s*64 + c*8 + th*4);
    bias = *(const float4*)(swt + boff + k_l*8 + th*4);
  };
  auto doItem = [&](const float4* S, float4* D, const float4* w4, float4 bias,
                    int k_l, int bl, int t, int KL, int KPL) {
    int p0 = 2*t*KPL + (k_l >> 1), p1 = p0 + KPL;
    int base = bl * 16;
    float4 A0 = S[scr(base + 2*p0)], A1 = S[scr(base + 2*p0 + 1)];
    float4 C0 = S[scr(base + 2*p1)], C1 = S[scr(base + 2*p1 + 1)];
    float4 a = bias;
    fma4(a, A0.x, w4[0]);  fma4(a, A0.y, w4[1]);  fma4(a, A0.z, w4[2]);  fma4(a, A0.w, w4[3]);
    fma4(a, A1.x, w4[4]);  fma4(a, A1.y, w4[5]);  fma4(a, A1.z, w4[6]);  fma4(a, A1.w, w4[7]);
    fma4(a, C0.x, w4[8]);  fma4(a, C0.y, w4[9]);  fma4(a, C0.z, w4[10]); fma4(a, C0.w, w4[11]);
    fma4(a, C1.x, w4[12]); fma4(a, C1.y, w4[13]); fma4(a, C1.z, w4[14]); fma4(a, C1.w, w4[15]);
    int r = t*KL + k_l;
    D[scr(base + 2*r + th)] = relu4(a);
  };

  { // level 8: sA(v7) -> sB ; local K=2, Kp=1, T=4
    int k_l = g & 1, bl = (g >> 1) & 31, t0 = (g >> 6) * 2;
    float4 w4[16], bias; loadW(0, 1792, k_l, w4, bias);
#pragma unroll
    for (int it = 0; it < 2; ++it) doItem(sA, sB, w4, bias, k_l, bl, t0 + it, 2, 1);
  }
  __syncthreads();
  { // level 9: sB -> sA ; K=4, Kp=2, T=2
    int k_l = g & 3, bl = g >> 2;
    float4 w4[16], bias; loadW(256, 1808, k_l, w4, bias);
#pragma unroll
    for (int it = 0; it < 2; ++it) doItem(sB, sA, w4, bias, k_l, bl, it, 4, 2);
  }
  __syncthreads();
  { // level 10: sA -> sB ; K=8, Kp=4, T=1
    int k_l = g & 7, bo = g >> 3;
    float4 w4[16], bias; loadW(768, 1840, k_l, w4, bias);
#pragma unroll
    for (int it = 0; it < 2; ++it) doItem(sA, sB, w4, bias, k_l, bo + it*16, 0, 8, 4);
  }
  __syncthreads();
  { // dense: out[b, (8j+k)*16+f] = sum_c v10[k][c] * fea[8j+k][c][f]
    int ch = tid & 7, b_l = tid >> 3;    // 8 chunks x 32 batches
    float* op = out + ((size_t)(b0 + b_l)) * 16384 + j * 128;
#pragma unroll
    for (int it = 0; it < 4; ++it) {
      int cc = ch + it*8, k = cc >> 2, fq = cc & 3;
      float4 s0 = sB[scr(b_l*16 + k*2)];
      float4 s1 = sB[scr(b_l*16 + k*2 + 1)];
      float sc[8] = {s0.x,s0.y,s0.z,s0.w,s1.x,s1.y,s1.z,s1.w};
      float4 acc = make_float4(0.f, 0.f, 0.f, 0.f);
#pragma unroll
      for (int c = 0; c < 8; ++c) {
        float4 fv = *(const float4*)(swt + 1904 + k*128 + c*16 + fq*4);
        acc.x = fmaf(sc[c], fv.x, acc.x); acc.y = fmaf(sc[c], fv.y, acc.y);
        acc.z = fmaf(sc[c], fv.z, acc.z); acc.w = fmaf(sc[c], fv.w, acc.w);
      }
      *(float4*)(op + k*16 + fq*4) = acc;
    }
  }
}

extern "C" void kernel_launch(void* const* d_in, const int* in_sizes, int n_in,
                              void* d_out, int out_size, void* d_ws, size_t ws_size,
                              hipStream_t stream) {
  const float* x  = (const float*)d_in[0];
  const float* F  = (const float*)d_in[1];
  const float* fb = (const float*)d_in[2];
  WPtrs P;
  for (int l = 0; l < 7; ++l) {
    P.W[l]  = (const float*)d_in[3 + 2 * l];
    P.Bv[l] = (const float*)d_in[4 + 2 * l];
  }
  const float* W8  = (const float*)d_in[17];
  const float* B8  = (const float*)d_in[18];
  const float* W9  = (const float*)d_in[19];
  const float* B9  = (const float*)d_in[20];
  const float* W10 = (const float*)d_in[21];
  const float* B10 = (const float*)d_in[22];
  const float* fea = (const float*)d_in[23];
  float* ws = (float*)d_ws;   // 128*1024*64 floats = 33.5 MB
  float* out = (float*)d_out;

  bfly_k1<<<dim3(1024), dim3(NT1), 0, stream>>>(x, F, fb, P, ws);
  bfly_k2<<<dim3(128, 32), dim3(NT2), 0, stream>>>(ws, W8, B8, W9, B9, W10, B10, fea, out);
}